// Round 1
// baseline (362.559 us; speedup 1.0000x reference)
//
#include <hip/hip_runtime.h>
#include <hip/hip_bf16.h>

#define B_ 4
#define G_ 4096
#define F_ 256
#define U_ 128

typedef __bf16 v8bf __attribute__((ext_vector_type(8)));
typedef float f32x4 __attribute__((ext_vector_type(4)));

__device__ __forceinline__ unsigned short f2bf(float x) {
    union { float f; unsigned u; } v; v.f = x;
    unsigned r = v.u + 0x7FFFu + ((v.u >> 16) & 1u);
    return (unsigned short)(r >> 16);
}

typedef const __attribute__((address_space(1))) unsigned int* gas_t;
typedef __attribute__((address_space(3))) unsigned int* las_t;

// async global->LDS, 16B per lane; lds base must be wave-uniform (dest = base + lane*16)
__device__ __forceinline__ void gld16(const void* g, const void* l) {
    __builtin_amdgcn_global_load_lds((gas_t)(unsigned long long)g,
                                     (las_t)(unsigned)(unsigned long long)l, 16, 0, 0);
}

// ---------------- prep: transpose w,w2 [256][128]f32 -> wT [128][256]bf16 ----------------
__global__ __launch_bounds__(256) void k_transpose_w(
    const float* __restrict__ w, const float* __restrict__ w2,
    unsigned short* __restrict__ wT, unsigned short* __restrict__ w2T)
{
    const float* src = blockIdx.x ? w2 : w;
    unsigned short* dst = blockIdx.x ? w2T : wT;
    int u = threadIdx.x & 127, kh = (threadIdx.x >> 7) * 128;
    for (int k = 0; k < 128; ++k)
        dst[(size_t)u * F_ + kh + k] = f2bf(src[(size_t)(kh + k) * U_ + u]);
}

// ---------------- prep: transpose ai,aj [128][4096]f32 -> aiT/ajT [4096][128]bf16 -------
__global__ __launch_bounds__(256) void k_transpose_aiaj(
    const float* __restrict__ ai, const float* __restrict__ aj,
    unsigned short* __restrict__ aiT, unsigned short* __restrict__ ajT)
{
    __shared__ unsigned short s_t[64 * 128];
    int blk = blockIdx.x;
    const float* src = (blk < 64) ? ai : aj;
    unsigned short* dst = (blk < 64) ? aiT : ajT;
    int gtile = (blk & 63) * 64;
    int tid = threadIdx.x;
    int gl = tid & 63, ub = tid >> 6;
    #pragma unroll
    for (int i = 0; i < 32; ++i) {
        int u = ub * 32 + i;
        float v = src[(size_t)u * G_ + gtile + gl];
        int ad = ((gl << 8) + (u << 1)) ^ ((gl & 7) << 4);
        *(unsigned short*)((char*)s_t + ad) = f2bf(v);
    }
    __syncthreads();
    #pragma unroll
    for (int i = 0; i < 4; ++i) {
        int c = tid + 256 * i;           // 0..1023 chunks of 16B
        int r = c >> 4, gr = c & 15;
        int ad = ((r << 8) + (gr << 4)) ^ ((r & 7) << 4);
        uint4 v = *(const uint4*)((const char*)s_t + ad);
        *(uint4*)(dst + (size_t)(gtile + r) * U_ + gr * 8) = v;
    }
}

// ---------------- f = bf16(x@w) (+fT), g2 = f32(x@w_2) -> d_out ----------------
__global__ __launch_bounds__(256, 2) void k_gemm_f(
    const float* __restrict__ x,
    const unsigned short* __restrict__ wT, const unsigned short* __restrict__ w2T,
    unsigned short* __restrict__ f_ws, unsigned short* __restrict__ fT_ws,
    float* __restrict__ g2_out)
{
    __shared__ unsigned short s_xa[128 * 128];
    __shared__ unsigned short s_w[128 * 128];
    __shared__ unsigned short s_w2[128 * 128];
    const int tid = threadIdx.x;
    const int lane = tid & 63, w = tid >> 6;
    const int l15 = lane & 15, l4 = lane >> 4;
    const int wm = w >> 1, wn = w & 1;
    const int mrow0 = blockIdx.x * 128;

    f32x4 zz = {0.f, 0.f, 0.f, 0.f};
    f32x4 accf[4][4], accg[4][4];
    #pragma unroll
    for (int i = 0; i < 4; ++i)
        #pragma unroll
        for (int j = 0; j < 4; ++j) { accf[i][j] = zz; accg[i][j] = zz; }

    for (int kc = 0; kc < 2; ++kc) {
        if (kc) __syncthreads();
        {   // stage x tile (f32 -> bf16, swizzled)
            int m = tid >> 1, half = tid & 1;
            const float* src = x + (size_t)(mrow0 + m) * F_ + kc * 128 + half * 64;
            unsigned tmp32[32];
            #pragma unroll
            for (int i = 0; i < 16; ++i) {
                float4 v = *(const float4*)(src + i * 4);
                tmp32[i * 2 + 0] = (unsigned)f2bf(v.x) | ((unsigned)f2bf(v.y) << 16);
                tmp32[i * 2 + 1] = (unsigned)f2bf(v.z) | ((unsigned)f2bf(v.w) << 16);
            }
            #pragma unroll
            for (int gi2 = 0; gi2 < 8; ++gi2) {
                int ad = (m << 8) + ((half * 128 + gi2 * 16) ^ ((m & 7) << 4));
                *(uint4*)((char*)s_xa + ad) = *(const uint4*)(tmp32 + gi2 * 4);
            }
        }
        #pragma unroll
        for (int i = 0; i < 8; ++i) {     // stage wT / w2T chunks
            int c = w * 8 + i;
            int row = c * 4 + l4;
            int Wp = (l15 << 4) ^ ((row & 7) << 4);
            gld16((const char*)wT  + (size_t)row * 512 + kc * 256 + Wp, (const char*)s_w  + c * 1024);
            gld16((const char*)w2T + (size_t)row * 512 + kc * 256 + Wp, (const char*)s_w2 + c * 1024);
        }
        __syncthreads();
        #pragma unroll
        for (int ks = 0; ks < 4; ++ks) {
            int kb = 64 * ks + 16 * l4;
            v8bf a[4], b1[4], b2[4];
            #pragma unroll
            for (int mf = 0; mf < 4; ++mf) {
                int m = l15 + 16 * mf + 64 * wm;
                int ad = (m << 8) + (kb ^ ((m & 7) << 4));
                a[mf] = *(const v8bf*)((const char*)s_xa + ad);
            }
            #pragma unroll
            for (int nf = 0; nf < 4; ++nf) {
                int u = l15 + 16 * nf + 64 * wn;
                int ad = (u << 8) + (kb ^ ((u & 7) << 4));
                b1[nf] = *(const v8bf*)((const char*)s_w + ad);
                b2[nf] = *(const v8bf*)((const char*)s_w2 + ad);
            }
            #pragma unroll
            for (int mf = 0; mf < 4; ++mf)
                #pragma unroll
                for (int nf = 0; nf < 4; ++nf) {
                    accf[mf][nf] = __builtin_amdgcn_mfma_f32_16x16x32_bf16(a[mf], b1[nf], accf[mf][nf], 0, 0, 0);
                    accg[mf][nf] = __builtin_amdgcn_mfma_f32_16x16x32_bf16(a[mf], b2[nf], accg[mf][nf], 0, 0, 0);
                }
        }
    }
    // epilogue: f (bf16) + g2 (f32) direct
    #pragma unroll
    for (int mf = 0; mf < 4; ++mf)
        #pragma unroll
        for (int nf = 0; nf < 4; ++nf)
            #pragma unroll
            for (int r = 0; r < 4; ++r) {
                int m = 4 * l4 + r + 16 * mf + 64 * wm;
                int u = l15 + 16 * nf + 64 * wn;
                size_t o = (size_t)(mrow0 + m) * U_ + u;
                f_ws[o] = f2bf(accf[mf][nf][r]);
                g2_out[o] = accg[mf][nf][r];
            }
    // fT via LDS bounce (reuse s_xa)
    __syncthreads();
    #pragma unroll
    for (int mf = 0; mf < 4; ++mf)
        #pragma unroll
        for (int nf = 0; nf < 4; ++nf)
            #pragma unroll
            for (int r = 0; r < 4; ++r) {
                int m = 4 * l4 + r + 16 * mf + 64 * wm;
                int u = l15 + 16 * nf + 64 * wn;
                int ad = (m << 8) + ((u << 1) ^ ((m & 7) << 4));
                *(unsigned short*)((char*)s_xa + ad) = f2bf(accf[mf][nf][r]);
            }
    __syncthreads();
    {
        int u = tid >> 1, mhalf = tid & 1;
        int b = mrow0 >> 12, gb = mrow0 & 4095;
        #pragma unroll
        for (int cch = 0; cch < 8; ++cch) {
            union { unsigned short s[8]; uint4 v; } pk;
            #pragma unroll
            for (int j = 0; j < 8; ++j) {
                int m = mhalf * 64 + cch * 8 + j;
                pk.s[j] = *(const unsigned short*)((const char*)s_xa + ((m << 8) + ((u << 1) ^ ((m & 7) << 4))));
            }
            *(uint4*)(fT_ws + (size_t)(b * U_ + u) * G_ + gb + mhalf * 64 + cch * 8) = pk.v;
        }
    }
}

// ---------------- main fused: attn -> sigmoid gate (write) -> agg partial ----------------
__global__ __launch_bounds__(512, 2) void k_main(
    const float* __restrict__ adj, const float* __restrict__ b_a,
    const unsigned short* __restrict__ f_ws,   // [B][G][U] bf16
    const unsigned short* __restrict__ fT_ws,  // [B][U][G] bf16
    const unsigned short* __restrict__ aiT_ws, // [G][U] bf16
    const unsigned short* __restrict__ ajT_ws, // [G][U] bf16
    float* __restrict__ gate_out,              // [B][G][G] f32
    float* __restrict__ part)                  // [B][2][G][U] f32
{
    __shared__ unsigned short s_fg [128 * 128];
    __shared__ unsigned short s_fgT[128 * 128];
    __shared__ unsigned short s_ajT[128 * 128];
    __shared__ unsigned short s_gT [128 * 128];

    const int tid = threadIdx.x;
    const int lane = tid & 63, w = tid >> 6;
    const int l15 = lane & 15, l4 = lane >> 4;
    const int htile = blockIdx.x * 128;
    const int split = blockIdx.y;
    const int b = blockIdx.z;
    const int wg = w >> 2;    // attn g'-group: +64*wg
    const int wh = w & 3;     // attn h'-group: +32*wh
    const int awm = w >> 1;   // agg  h'-group: +32*awm
    const int awn = w & 1;    // agg  u-group : +64*awn

    // per-block constant B-fragments in registers
    v8bf aih[2][4], fh[2][4];
    #pragma unroll
    for (int nf = 0; nf < 2; ++nf) {
        int hp = l15 + 16 * nf + 32 * wh;
        const unsigned short* arow = aiT_ws + (size_t)(htile + hp) * U_;
        const unsigned short* frow = f_ws + ((size_t)b * G_ + htile + hp) * U_;
        #pragma unroll
        for (int ks = 0; ks < 4; ++ks) {
            int off = 32 * ks + 8 * l4;
            aih[nf][ks] = *(const v8bf*)(arow + off);
            fh[nf][ks]  = *(const v8bf*)(frow + off);
        }
    }

    f32x4 zz = {0.f, 0.f, 0.f, 0.f};
    f32x4 agga[2][4];
    #pragma unroll
    for (int i = 0; i < 2; ++i)
        #pragma unroll
        for (int j = 0; j < 4; ++j) agga[i][j] = zz;

    const char* fg_src  = (const char*)(f_ws + (size_t)b * G_ * U_);
    const char* ajT_src = (const char*)ajT_ws;
    const char* fgT_src = (const char*)(fT_ws + (size_t)b * U_ * G_);

    for (int it = 0; it < 16; ++it) {
        int gtile = split * 2048 + it * 128;
        __syncthreads();   // B1: previous-iter LDS readers done
        #pragma unroll
        for (int i = 0; i < 4; ++i) {
            int c = w * 4 + i;              // 0..31 (1KB chunks)
            int row = c * 4 + l4;           // 0..127
            int Wp = (l15 << 4) ^ ((row & 7) << 4);
            gld16(fg_src  + (size_t)(gtile + row) * 256 + Wp, (const char*)s_fg  + c * 1024);
            gld16(ajT_src + (size_t)(gtile + row) * 256 + Wp, (const char*)s_ajT + c * 1024);
            gld16(fgT_src + (size_t)row * 8192 + gtile * 2 + Wp, (const char*)s_fgT + c * 1024);
        }
        __syncthreads();   // B2: staging complete (vmcnt drained)

        // attn[g'][h'] = f@aiT' + ajT@f'  (both terms into one accumulator)
        f32x4 acc[4][2];
        #pragma unroll
        for (int mf = 0; mf < 4; ++mf)
            #pragma unroll
            for (int nf = 0; nf < 2; ++nf) acc[mf][nf] = zz;
        #pragma unroll
        for (int ks = 0; ks < 4; ++ks) {
            int kb = 64 * ks + 16 * l4;
            v8bf a1[4], a2[4];
            #pragma unroll
            for (int mf = 0; mf < 4; ++mf) {
                int gp = l15 + 16 * mf + 64 * wg;
                int ad = (gp << 8) + (kb ^ ((gp & 7) << 4));
                a1[mf] = *(const v8bf*)((const char*)s_fg + ad);
                a2[mf] = *(const v8bf*)((const char*)s_ajT + ad);
            }
            #pragma unroll
            for (int mf = 0; mf < 4; ++mf)
                #pragma unroll
                for (int nf = 0; nf < 2; ++nf) {
                    acc[mf][nf] = __builtin_amdgcn_mfma_f32_16x16x32_bf16(a1[mf], aih[nf][ks], acc[mf][nf], 0, 0, 0);
                    acc[mf][nf] = __builtin_amdgcn_mfma_f32_16x16x32_bf16(a2[mf], fh[nf][ks], acc[mf][nf], 0, 0, 0);
                }
        }

        // epilogue: bias + sigmoid -> gate (global, f32) + gate^T (LDS, bf16)
        #pragma unroll
        for (int mf = 0; mf < 4; ++mf)
            #pragma unroll
            for (int nf = 0; nf < 2; ++nf) {
                int hp = l15 + 16 * nf + 32 * wh;
                int hcol = htile + hp;
                #pragma unroll
                for (int r = 0; r < 4; ++r) {
                    int gp = 4 * l4 + r + 16 * mf + 64 * wg;
                    size_t gi = (size_t)(gtile + gp) * G_ + hcol;
                    float adjv = adj[gi];
                    float bav = b_a[gi];
                    float attn = acc[mf][nf][r] + bav + fmaf(adjv, 1e9f, -1e9f);
                    float e = __expf(-attn);
                    float gv = __builtin_amdgcn_rcpf(1.0f + e);
                    gate_out[((size_t)b << 24) + gi] = gv;
                    int ad = (hp << 8) + ((gp << 1) ^ ((hp & 7) << 4));
                    *(unsigned short*)((char*)s_gT + ad) = f2bf(gv);
                }
            }
        __syncthreads();   // B3: gate^T ready

        // agg[h'][u] += gate^T @ f
        #pragma unroll
        for (int ks = 0; ks < 4; ++ks) {
            int kb = 64 * ks + 16 * l4;
            v8bf ag[2], bf[4];
            #pragma unroll
            for (int mf = 0; mf < 2; ++mf) {
                int hp = l15 + 16 * mf + 32 * awm;
                int ad = (hp << 8) + (kb ^ ((hp & 7) << 4));
                ag[mf] = *(const v8bf*)((const char*)s_gT + ad);
            }
            #pragma unroll
            for (int nf = 0; nf < 4; ++nf) {
                int up = l15 + 16 * nf + 64 * awn;
                int ad = (up << 8) + (kb ^ ((up & 7) << 4));
                bf[nf] = *(const v8bf*)((const char*)s_fgT + ad);
            }
            #pragma unroll
            for (int mf = 0; mf < 2; ++mf)
                #pragma unroll
                for (int nf = 0; nf < 4; ++nf)
                    agga[mf][nf] = __builtin_amdgcn_mfma_f32_16x16x32_bf16(ag[mf], bf[nf], agga[mf][nf], 0, 0, 0);
        }
    }

    // write agg partial
    #pragma unroll
    for (int mf = 0; mf < 2; ++mf)
        #pragma unroll
        for (int nf = 0; nf < 4; ++nf) {
            int up = l15 + 16 * nf + 64 * awn;
            #pragma unroll
            for (int r = 0; r < 4; ++r) {
                int hp = 4 * l4 + r + 16 * mf + 32 * awm;
                part[(((size_t)b * 2 + split) << 19) + (size_t)(htile + hp) * U_ + up] = agga[mf][nf][r];
            }
        }
}

// ---------------- reduce: out = relu(part0 + part1 + g2) (g2 already in d_out) ----------
__global__ __launch_bounds__(256) void k_reduce(const float4* __restrict__ part, float4* __restrict__ outio)
{
    int i = blockIdx.x * 256 + threadIdx.x;     // 0..524287 float4s
    int fb = i >> 17, r = i & 0x1FFFF;
    float4 p0 = part[((size_t)(fb * 2) << 17) + r];
    float4 p1 = part[((size_t)(fb * 2 + 1) << 17) + r];
    float4 g = outio[i];
    float4 o;
    o.x = fmaxf(p0.x + p1.x + g.x, 0.f);
    o.y = fmaxf(p0.y + p1.y + g.y, 0.f);
    o.z = fmaxf(p0.z + p1.z + g.z, 0.f);
    o.w = fmaxf(p0.w + p1.w + g.w, 0.f);
    outio[i] = o;
}

extern "C" void kernel_launch(void* const* d_in, const int* in_sizes, int n_in,
                              void* d_out, int out_size, void* d_ws, size_t ws_size,
                              hipStream_t stream)
{
    (void)in_sizes; (void)n_in; (void)out_size; (void)ws_size;
    const float* x   = (const float*)d_in[0];
    const float* adj = (const float*)d_in[1];
    const float* w   = (const float*)d_in[2];
    const float* ai  = (const float*)d_in[3];
    const float* aj  = (const float*)d_in[4];
    const float* w2  = (const float*)d_in[5];
    const float* ba  = (const float*)d_in[6];

    char* ws = (char*)d_ws;
    unsigned short* f_ws  = (unsigned short*)(ws);                       // 4 MiB bf16 [B][G][U]
    unsigned short* fT_ws = (unsigned short*)(ws + ((size_t)4 << 20));   // 4 MiB bf16 [B][U][G]
    unsigned short* aiT   = (unsigned short*)(ws + ((size_t)8 << 20));   // 1 MiB
    unsigned short* ajT   = (unsigned short*)(ws + ((size_t)9 << 20));   // 1 MiB
    unsigned short* wT    = (unsigned short*)(ws + ((size_t)10 << 20));  // 64 KiB
    unsigned short* w2T   = (unsigned short*)(ws + ((size_t)10 << 20) + (1 << 17));
    float* part           = (float*)(ws + ((size_t)11 << 20));           // 16 MiB

    float* out  = (float*)d_out;                       // [B*G*U]
    float* gate = out + (size_t)B_ * G_ * U_;          // [B*G*G]

    k_transpose_w   <<<dim3(2),        dim3(256), 0, stream>>>(w, w2, wT, w2T);
    k_transpose_aiaj<<<dim3(128),      dim3(256), 0, stream>>>(ai, aj, aiT, ajT);
    k_gemm_f        <<<dim3(128),      dim3(256), 0, stream>>>(x, wT, w2T, f_ws, fT_ws, out);
    k_main          <<<dim3(32, 2, 4), dim3(512), 0, stream>>>(adj, ba, f_ws, fT_ws, aiT, ajT, gate, part);
    k_reduce        <<<dim3(2048),     dim3(256), 0, stream>>>((const float4*)part, (float4*)out);
}

// Round 2
// 219.561 us; speedup vs baseline: 1.6513x; 1.6513x over previous
//
#include <hip/hip_runtime.h>
#include <hip/hip_bf16.h>

#define B_ 4
#define G_ 4096
#define F_ 256
#define U_ 128

typedef __bf16 v8bf __attribute__((ext_vector_type(8)));
typedef __bf16 v4bf __attribute__((ext_vector_type(4)));
typedef float f32x4 __attribute__((ext_vector_type(4)));

__device__ __forceinline__ unsigned short f2bf(float x) {
    union { float f; unsigned u; } v; v.f = x;
    unsigned r = v.u + 0x7FFFu + ((v.u >> 16) & 1u);
    return (unsigned short)(r >> 16);
}

typedef const __attribute__((address_space(1))) unsigned int* gas_t;
typedef __attribute__((address_space(3))) unsigned int* las_t;

// async global->LDS, 16B per lane; lds base must be wave-uniform (dest = base + lane*16)
__device__ __forceinline__ void gld16(const void* g, const void* l) {
    __builtin_amdgcn_global_load_lds((gas_t)(unsigned long long)g,
                                     (las_t)(unsigned)(unsigned long long)l, 16, 0, 0);
}

// ---------------- prep: transpose w,w2 [256][128]f32 -> wT [128][256]bf16 ----------------
__global__ __launch_bounds__(256) void k_transpose_w(
    const float* __restrict__ w, const float* __restrict__ w2,
    unsigned short* __restrict__ wT, unsigned short* __restrict__ w2T)
{
    const float* src = blockIdx.x ? w2 : w;
    unsigned short* dst = blockIdx.x ? w2T : wT;
    int u = threadIdx.x & 127, kh = (threadIdx.x >> 7) * 128;
    for (int k = 0; k < 128; ++k)
        dst[(size_t)u * F_ + kh + k] = f2bf(src[(size_t)(kh + k) * U_ + u]);
}

// ---------------- prep: transpose ai,aj [128][4096]f32 -> aiT/ajT [4096][128]bf16 -------
__global__ __launch_bounds__(256) void k_transpose_aiaj(
    const float* __restrict__ ai, const float* __restrict__ aj,
    unsigned short* __restrict__ aiT, unsigned short* __restrict__ ajT)
{
    __shared__ unsigned short s_t[64 * 128];
    int blk = blockIdx.x;
    const float* src = (blk < 64) ? ai : aj;
    unsigned short* dst = (blk < 64) ? aiT : ajT;
    int gtile = (blk & 63) * 64;
    int tid = threadIdx.x;
    int gl = tid & 63, ub = tid >> 6;
    #pragma unroll
    for (int i = 0; i < 32; ++i) {
        int u = ub * 32 + i;
        float v = src[(size_t)u * G_ + gtile + gl];
        int ad = ((gl << 8) + (u << 1)) ^ ((gl & 7) << 4);
        *(unsigned short*)((char*)s_t + ad) = f2bf(v);
    }
    __syncthreads();
    #pragma unroll
    for (int i = 0; i < 4; ++i) {
        int c = tid + 256 * i;           // 0..1023 chunks of 16B
        int r = c >> 4, gr = c & 15;
        int ad = ((r << 8) + (gr << 4)) ^ ((r & 7) << 4);
        uint4 v = *(const uint4*)((const char*)s_t + ad);
        *(uint4*)(dst + (size_t)(gtile + r) * U_ + gr * 8) = v;
    }
}

// ---------------- prep: fused bias, transposed: ct[h][g] = bf16(b_a[g][h] - 1e9*(1-adj[g][h]))
__global__ __launch_bounds__(256) void k_bias(
    const float* __restrict__ adj, const float* __restrict__ b_a,
    unsigned short* __restrict__ ct)
{
    __shared__ unsigned short s_t[64 * 64];  // [h][g] bf16, swizzled
    int g0 = blockIdx.x * 64, h0 = blockIdx.y * 64;
    int tid = threadIdx.x;
    int hl = tid & 63, gb = tid >> 6;        // gb 0..3
    #pragma unroll
    for (int i = 0; i < 16; ++i) {
        int gl = gb * 16 + i;
        size_t gi = (size_t)(g0 + gl) * G_ + h0 + hl;
        float v = fmaf(adj[gi], 1e9f, -1e9f) + b_a[gi];
        int ad = ((hl << 7) + (gl << 1)) ^ ((hl & 7) << 4);
        *(unsigned short*)((char*)s_t + ad) = f2bf(v);
    }
    __syncthreads();
    #pragma unroll
    for (int i = 0; i < 2; ++i) {
        int c = tid + 256 * i;               // 0..511 chunks of 16B
        int r = c >> 3, off = c & 7;         // r = h row
        int ad = ((r << 7) + (off << 4)) ^ ((r & 7) << 4);
        uint4 v = *(const uint4*)((const char*)s_t + ad);
        *(uint4*)(ct + (size_t)(h0 + r) * G_ + g0 + off * 8) = v;
    }
}

// ---------------- f = bf16(x@w) (+fT), g2 = f32(x@w_2) -> d_out ----------------
__global__ __launch_bounds__(256, 2) void k_gemm_f(
    const float* __restrict__ x,
    const unsigned short* __restrict__ wT, const unsigned short* __restrict__ w2T,
    unsigned short* __restrict__ f_ws, unsigned short* __restrict__ fT_ws,
    float* __restrict__ g2_out)
{
    __shared__ unsigned short s_xa[128 * 128];
    __shared__ unsigned short s_w[128 * 128];
    __shared__ unsigned short s_w2[128 * 128];
    const int tid = threadIdx.x;
    const int lane = tid & 63, w = tid >> 6;
    const int l15 = lane & 15, l4 = lane >> 4;
    const int wm = w >> 1, wn = w & 1;
    const int mrow0 = blockIdx.x * 128;

    f32x4 zz = {0.f, 0.f, 0.f, 0.f};
    f32x4 accf[4][4], accg[4][4];
    #pragma unroll
    for (int i = 0; i < 4; ++i)
        #pragma unroll
        for (int j = 0; j < 4; ++j) { accf[i][j] = zz; accg[i][j] = zz; }

    for (int kc = 0; kc < 2; ++kc) {
        if (kc) __syncthreads();
        {   // stage x tile (f32 -> bf16, swizzled)
            int m = tid >> 1, half = tid & 1;
            const float* src = x + (size_t)(mrow0 + m) * F_ + kc * 128 + half * 64;
            unsigned tmp32[32];
            #pragma unroll
            for (int i = 0; i < 16; ++i) {
                float4 v = *(const float4*)(src + i * 4);
                tmp32[i * 2 + 0] = (unsigned)f2bf(v.x) | ((unsigned)f2bf(v.y) << 16);
                tmp32[i * 2 + 1] = (unsigned)f2bf(v.z) | ((unsigned)f2bf(v.w) << 16);
            }
            #pragma unroll
            for (int gi2 = 0; gi2 < 8; ++gi2) {
                int ad = (m << 8) + ((half * 128 + gi2 * 16) ^ ((m & 7) << 4));
                *(uint4*)((char*)s_xa + ad) = *(const uint4*)(tmp32 + gi2 * 4);
            }
        }
        #pragma unroll
        for (int i = 0; i < 8; ++i) {     // stage wT / w2T chunks
            int c = w * 8 + i;
            int row = c * 4 + l4;
            int Wp = (l15 << 4) ^ ((row & 7) << 4);
            gld16((const char*)wT  + (size_t)row * 512 + kc * 256 + Wp, (const char*)s_w  + c * 1024);
            gld16((const char*)w2T + (size_t)row * 512 + kc * 256 + Wp, (const char*)s_w2 + c * 1024);
        }
        __syncthreads();
        #pragma unroll
        for (int ks = 0; ks < 4; ++ks) {
            int kb = 64 * ks + 16 * l4;
            v8bf a[4], b1[4], b2[4];
            #pragma unroll
            for (int mf = 0; mf < 4; ++mf) {
                int m = l15 + 16 * mf + 64 * wm;
                int ad = (m << 8) + (kb ^ ((m & 7) << 4));
                a[mf] = *(const v8bf*)((const char*)s_xa + ad);
            }
            #pragma unroll
            for (int nf = 0; nf < 4; ++nf) {
                int u = l15 + 16 * nf + 64 * wn;
                int ad = (u << 8) + (kb ^ ((u & 7) << 4));
                b1[nf] = *(const v8bf*)((const char*)s_w + ad);
                b2[nf] = *(const v8bf*)((const char*)s_w2 + ad);
            }
            #pragma unroll
            for (int mf = 0; mf < 4; ++mf)
                #pragma unroll
                for (int nf = 0; nf < 4; ++nf) {
                    accf[mf][nf] = __builtin_amdgcn_mfma_f32_16x16x32_bf16(a[mf], b1[nf], accf[mf][nf], 0, 0, 0);
                    accg[mf][nf] = __builtin_amdgcn_mfma_f32_16x16x32_bf16(a[mf], b2[nf], accg[mf][nf], 0, 0, 0);
                }
        }
    }
    // epilogue: f (bf16) + g2 (f32) direct
    #pragma unroll
    for (int mf = 0; mf < 4; ++mf)
        #pragma unroll
        for (int nf = 0; nf < 4; ++nf)
            #pragma unroll
            for (int r = 0; r < 4; ++r) {
                int m = 4 * l4 + r + 16 * mf + 64 * wm;
                int u = l15 + 16 * nf + 64 * wn;
                size_t o = (size_t)(mrow0 + m) * U_ + u;
                f_ws[o] = f2bf(accf[mf][nf][r]);
                g2_out[o] = accg[mf][nf][r];
            }
    // fT via LDS bounce (reuse s_xa)
    __syncthreads();
    #pragma unroll
    for (int mf = 0; mf < 4; ++mf)
        #pragma unroll
        for (int nf = 0; nf < 4; ++nf)
            #pragma unroll
            for (int r = 0; r < 4; ++r) {
                int m = 4 * l4 + r + 16 * mf + 64 * wm;
                int u = l15 + 16 * nf + 64 * wn;
                int ad = (m << 8) + ((u << 1) ^ ((m & 7) << 4));
                *(unsigned short*)((char*)s_xa + ad) = f2bf(accf[mf][nf][r]);
            }
    __syncthreads();
    {
        int u = tid >> 1, mhalf = tid & 1;
        int b = mrow0 >> 12, gb = mrow0 & 4095;
        #pragma unroll
        for (int cch = 0; cch < 8; ++cch) {
            union { unsigned short s[8]; uint4 v; } pk;
            #pragma unroll
            for (int j = 0; j < 8; ++j) {
                int m = mhalf * 64 + cch * 8 + j;
                pk.s[j] = *(const unsigned short*)((const char*)s_xa + ((m << 8) + ((u << 1) ^ ((m & 7) << 4))));
            }
            *(uint4*)(fT_ws + (size_t)(b * U_ + u) * G_ + gb + mhalf * 64 + cch * 8) = pk.v;
        }
    }
}

// ---------------- main fused: attn -> sigmoid gate (write) -> agg partial ----------------
__global__ __launch_bounds__(512, 2) void k_main(
    const unsigned short* __restrict__ ct_ws,  // [G][G] bf16 fused bias (transposed: [h][g])
    const unsigned short* __restrict__ f_ws,   // [B][G][U] bf16
    const unsigned short* __restrict__ fT_ws,  // [B][U][G] bf16
    const unsigned short* __restrict__ aiT_ws, // [G][U] bf16
    const unsigned short* __restrict__ ajT_ws, // [G][U] bf16
    float* __restrict__ gate_out,              // [B][G][G] f32
    float* __restrict__ part)                  // [B][2][G][U] f32
{
    __shared__ unsigned short s_fg [128 * 128];
    __shared__ unsigned short s_fgT[128 * 128];
    __shared__ unsigned short s_ajT[128 * 128];
    __shared__ unsigned short s_gT [128 * 128];

    const int tid = threadIdx.x;
    const int lane = tid & 63, w = tid >> 6;
    const int l15 = lane & 15, l4 = lane >> 4;
    const int htile = blockIdx.x * 128;
    const int split = blockIdx.y;
    const int b = blockIdx.z;
    const int wg = w >> 2;    // attn g'-group: +64*wg
    const int wh = w & 3;     // attn h'-group: +32*wh
    const int awm = w >> 1;   // agg  h'-group: +32*awm
    const int awn = w & 1;    // agg  u-group : +64*awn

    // per-block constant B-fragments in registers
    v8bf aih[2][4], fh[2][4];
    #pragma unroll
    for (int nf = 0; nf < 2; ++nf) {
        int hp = l15 + 16 * nf + 32 * wh;
        const unsigned short* arow = aiT_ws + (size_t)(htile + hp) * U_;
        const unsigned short* frow = f_ws + ((size_t)b * G_ + htile + hp) * U_;
        #pragma unroll
        for (int ks = 0; ks < 4; ++ks) {
            int off = 32 * ks + 8 * l4;
            aih[nf][ks] = *(const v8bf*)(arow + off);
            fh[nf][ks]  = *(const v8bf*)(frow + off);
        }
    }

    f32x4 zz = {0.f, 0.f, 0.f, 0.f};
    f32x4 agga[2][4];
    #pragma unroll
    for (int i = 0; i < 2; ++i)
        #pragma unroll
        for (int j = 0; j < 4; ++j) agga[i][j] = zz;

    const char* fg_src  = (const char*)(f_ws + (size_t)b * G_ * U_);
    const char* ajT_src = (const char*)ajT_ws;
    const char* fgT_src = (const char*)(fT_ws + (size_t)b * U_ * G_);

    for (int it = 0; it < 16; ++it) {
        int gtile = split * 2048 + it * 128;
        __syncthreads();   // B1: previous-iter LDS readers done
        #pragma unroll
        for (int i = 0; i < 4; ++i) {
            int c = w * 4 + i;              // 0..31 (1KB chunks)
            int row = c * 4 + l4;           // 0..127
            int Wp = (l15 << 4) ^ ((row & 7) << 4);
            gld16(fg_src  + (size_t)(gtile + row) * 256 + Wp, (const char*)s_fg  + c * 1024);
            gld16(ajT_src + (size_t)(gtile + row) * 256 + Wp, (const char*)s_ajT + c * 1024);
            gld16(fgT_src + (size_t)row * 8192 + gtile * 2 + Wp, (const char*)s_fgT + c * 1024);
        }
        // prefetch fused-bias fragments; complete for free under B2's vmcnt drain
        v4bf ctv[4][2];
        #pragma unroll
        for (int mf = 0; mf < 4; ++mf)
            #pragma unroll
            for (int nf = 0; nf < 2; ++nf) {
                int hp = l15 + 16 * nf + 32 * wh;
                int gp0 = 4 * l4 + 16 * mf + 64 * wg;
                ctv[mf][nf] = *(const v4bf*)(ct_ws + (size_t)(htile + hp) * G_ + gtile + gp0);
            }
        __syncthreads();   // B2: staging complete (vmcnt drained)

        // attn[g'][h'] = f@aiT' + ajT@f'  (both terms into one accumulator)
        f32x4 acc[4][2];
        #pragma unroll
        for (int mf = 0; mf < 4; ++mf)
            #pragma unroll
            for (int nf = 0; nf < 2; ++nf) acc[mf][nf] = zz;
        #pragma unroll
        for (int ks = 0; ks < 4; ++ks) {
            int kb = 64 * ks + 16 * l4;
            v8bf a1[4], a2[4];
            #pragma unroll
            for (int mf = 0; mf < 4; ++mf) {
                int gp = l15 + 16 * mf + 64 * wg;
                int ad = (gp << 8) + (kb ^ ((gp & 7) << 4));
                a1[mf] = *(const v8bf*)((const char*)s_fg + ad);
                a2[mf] = *(const v8bf*)((const char*)s_ajT + ad);
            }
            #pragma unroll
            for (int mf = 0; mf < 4; ++mf)
                #pragma unroll
                for (int nf = 0; nf < 2; ++nf) {
                    acc[mf][nf] = __builtin_amdgcn_mfma_f32_16x16x32_bf16(a1[mf], aih[nf][ks], acc[mf][nf], 0, 0, 0);
                    acc[mf][nf] = __builtin_amdgcn_mfma_f32_16x16x32_bf16(a2[mf], fh[nf][ks], acc[mf][nf], 0, 0, 0);
                }
        }

        // epilogue: bias + sigmoid -> gate (global, f32) + gate^T (LDS, bf16)
        #pragma unroll
        for (int mf = 0; mf < 4; ++mf)
            #pragma unroll
            for (int nf = 0; nf < 2; ++nf) {
                int hp = l15 + 16 * nf + 32 * wh;
                int hcol = htile + hp;
                #pragma unroll
                for (int r = 0; r < 4; ++r) {
                    int gp = 4 * l4 + r + 16 * mf + 64 * wg;
                    float attn = acc[mf][nf][r] + (float)ctv[mf][nf][r];
                    float e = __expf(-attn);
                    float gv = __builtin_amdgcn_rcpf(1.0f + e);
                    gate_out[((size_t)b << 24) + (size_t)(gtile + gp) * G_ + hcol] = gv;
                    int ad = (hp << 8) + ((gp << 1) ^ ((hp & 7) << 4));
                    *(unsigned short*)((char*)s_gT + ad) = f2bf(gv);
                }
            }
        __syncthreads();   // B3: gate^T ready

        // agg[h'][u] += gate^T @ f
        #pragma unroll
        for (int ks = 0; ks < 4; ++ks) {
            int kb = 64 * ks + 16 * l4;
            v8bf ag[2], bf[4];
            #pragma unroll
            for (int mf = 0; mf < 2; ++mf) {
                int hp = l15 + 16 * mf + 32 * awm;
                int ad = (hp << 8) + (kb ^ ((hp & 7) << 4));
                ag[mf] = *(const v8bf*)((const char*)s_gT + ad);
            }
            #pragma unroll
            for (int nf = 0; nf < 4; ++nf) {
                int up = l15 + 16 * nf + 64 * awn;
                int ad = (up << 8) + (kb ^ ((up & 7) << 4));
                bf[nf] = *(const v8bf*)((const char*)s_fgT + ad);
            }
            #pragma unroll
            for (int mf = 0; mf < 2; ++mf)
                #pragma unroll
                for (int nf = 0; nf < 4; ++nf)
                    agga[mf][nf] = __builtin_amdgcn_mfma_f32_16x16x32_bf16(ag[mf], bf[nf], agga[mf][nf], 0, 0, 0);
        }
    }

    // write agg partial
    #pragma unroll
    for (int mf = 0; mf < 2; ++mf)
        #pragma unroll
        for (int nf = 0; nf < 4; ++nf) {
            int up = l15 + 16 * nf + 64 * awn;
            #pragma unroll
            for (int r = 0; r < 4; ++r) {
                int hp = 4 * l4 + r + 16 * mf + 32 * awm;
                part[(((size_t)b * 2 + split) << 19) + (size_t)(htile + hp) * U_ + up] = agga[mf][nf][r];
            }
        }
}

// ---------------- reduce: out = relu(part0 + part1 + g2) (g2 already in d_out) ----------
__global__ __launch_bounds__(256) void k_reduce(const float4* __restrict__ part, float4* __restrict__ outio)
{
    int i = blockIdx.x * 256 + threadIdx.x;     // 0..524287 float4s
    int fb = i >> 17, r = i & 0x1FFFF;
    float4 p0 = part[((size_t)(fb * 2) << 17) + r];
    float4 p1 = part[((size_t)(fb * 2 + 1) << 17) + r];
    float4 g = outio[i];
    float4 o;
    o.x = fmaxf(p0.x + p1.x + g.x, 0.f);
    o.y = fmaxf(p0.y + p1.y + g.y, 0.f);
    o.z = fmaxf(p0.z + p1.z + g.z, 0.f);
    o.w = fmaxf(p0.w + p1.w + g.w, 0.f);
    outio[i] = o;
}

extern "C" void kernel_launch(void* const* d_in, const int* in_sizes, int n_in,
                              void* d_out, int out_size, void* d_ws, size_t ws_size,
                              hipStream_t stream)
{
    (void)in_sizes; (void)n_in; (void)out_size; (void)ws_size;
    const float* x   = (const float*)d_in[0];
    const float* adj = (const float*)d_in[1];
    const float* w   = (const float*)d_in[2];
    const float* ai  = (const float*)d_in[3];
    const float* aj  = (const float*)d_in[4];
    const float* w2  = (const float*)d_in[5];
    const float* ba  = (const float*)d_in[6];

    char* ws = (char*)d_ws;
    unsigned short* f_ws  = (unsigned short*)(ws);                       // 4 MiB bf16 [B][G][U]
    unsigned short* fT_ws = (unsigned short*)(ws + ((size_t)4 << 20));   // 4 MiB bf16 [B][U][G]
    unsigned short* aiT   = (unsigned short*)(ws + ((size_t)8 << 20));   // 1 MiB
    unsigned short* ajT   = (unsigned short*)(ws + ((size_t)9 << 20));   // 1 MiB
    unsigned short* wT    = (unsigned short*)(ws + ((size_t)10 << 20));  // 64 KiB
    unsigned short* w2T   = (unsigned short*)(ws + ((size_t)10 << 20) + (1 << 17));
    float* part           = (float*)(ws + ((size_t)11 << 20));           // 16 MiB
    unsigned short* ct    = (unsigned short*)(ws + ((size_t)27 << 20));  // 32 MiB bf16 [G][G] (h-major)

    float* out  = (float*)d_out;                       // [B*G*U]
    float* gate = out + (size_t)B_ * G_ * U_;          // [B*G*G]

    k_transpose_w   <<<dim3(2),        dim3(256), 0, stream>>>(w, w2, wT, w2T);
    k_transpose_aiaj<<<dim3(128),      dim3(256), 0, stream>>>(ai, aj, aiT, ajT);
    k_bias          <<<dim3(64, 64),   dim3(256), 0, stream>>>(adj, ba, ct);
    k_gemm_f        <<<dim3(128),      dim3(256), 0, stream>>>(x, wT, w2T, f_ws, fT_ws, out);
    k_main          <<<dim3(32, 2, 4), dim3(512), 0, stream>>>(ct, f_ws, fT_ws, aiT, ajT, gate, part);
    k_reduce        <<<dim3(2048),     dim3(256), 0, stream>>>((const float4*)part, (float4*)out);
}